// Round 3
// baseline (3520.296 us; speedup 1.0000x reference)
//
#include <hip/hip_runtime.h>
#include <hip/hip_bf16.h>
#include <stdint.h>

typedef __attribute__((ext_vector_type(8))) short short8;
typedef __attribute__((ext_vector_type(4))) float f32x4;
typedef __hip_bfloat16 bf16;

#define MFMA16(a, b, c) __builtin_amdgcn_mfma_f32_16x16x32_bf16(a, b, c, 0, 0, 0)

// XOR swizzle within a row: spreads 16B column-slots across banks (G4).
__device__ __forceinline__ uint32_t swz(uint32_t row, uint32_t bir) {
  return bir ^ ((row & 7u) << 4);
}

__device__ __forceinline__ short f2bs(float v) {          // f32 -> bf16 bits (RTNE)
  bf16 b = __float2bfloat16(v);
  return *reinterpret_cast<short*>(&b);
}

// load 8 consecutive float-tensor elements as bf16 bits, dtype-flag-driven
__device__ __forceinline__ short8 load8(const void* p, int eidx, int f32) {
  short8 r;
  if (f32) {
    const float* f = (const float*)p + eidx;
    f32x4 a = *reinterpret_cast<const f32x4*>(f);
    f32x4 b = *reinterpret_cast<const f32x4*>(f + 4);
    r[0] = f2bs(a[0]); r[1] = f2bs(a[1]); r[2] = f2bs(a[2]); r[3] = f2bs(a[3]);
    r[4] = f2bs(b[0]); r[5] = f2bs(b[1]); r[6] = f2bs(b[2]); r[7] = f2bs(b[3]);
  } else {
    r = *reinterpret_cast<const short8*>((const bf16*)p + eidx);
  }
  return r;
}
__device__ __forceinline__ float ldf(const void* p, int eidx, int f32) {
  return f32 ? ((const float*)p)[eidx] : __bfloat162float(((const bf16*)p)[eidx]);
}

// ---------------------------------------------------------------------------
// Probe: decide whether float input tensors are f32 or bf16 on device.
// Even-index uint16s of x: f32 -> low mantissa halves (uniform, ~44% have
// exp>=0x90); bf16 -> genuine N(0,1) values (exp <= ~0x82, count == 0).
// ---------------------------------------------------------------------------
__global__ void k_probe(const unsigned short* __restrict__ xu, int* __restrict__ flag) {
  int lane = threadIdx.x;  // 64 threads
  int cnt = 0;
  for (int i = lane * 2; i < 4096; i += 128) {
    unsigned short u = xu[i];
    int e = (u >> 7) & 0xFF;
    cnt += (e >= 0x90);
  }
  #pragma unroll
  for (int o = 1; o < 64; o <<= 1) cnt += __shfl_xor(cnt, o);
  if (lane == 0) *flag = (cnt > 100) ? 1 : 0;  // 1 => tensors are f32
}

// ---------------------------------------------------------------------------
// Kernel 1: per-window fused QKV projection + windowed attention.
// grid = 2592 windows, block = 256 threads (4 waves). ~112 KB LDS.
// ---------------------------------------------------------------------------
__global__ __launch_bounds__(256) void k_win_attn(
    const void* __restrict__ x,        // [8*15876, 512] f32 (probe-verified)
    const void* __restrict__ wqkv,     // [1536, 512]
    const void* __restrict__ bqkv,     // [1536]
    const void* __restrict__ rpe,      // [169, 8]
    const int*  __restrict__ relidx,   // [49, 49]
    bf16* __restrict__ attn_out,       // [2592*49, 512] always bf16 (internal ws)
    const int* __restrict__ dflag)
{
  __shared__ __align__(16) char sX[64 * 1024];
  __shared__ __align__(16) char sQ[64 * 128];
  __shared__ __align__(16) char sK[64 * 128];
  __shared__ __align__(16) char sVt[64 * 128];
  __shared__ float sS[64 * 65];
  __shared__ __align__(16) char sP[64 * 128];

  const int f32 = *dflag;

  const int tid  = threadIdx.x;
  const int lane = tid & 63;
  const int wid  = tid >> 6;
  const int r16  = lane & 15;
  const int hi   = lane >> 4;

  const int wi = blockIdx.x;
  const int bb = wi / 324;
  const int qr = wi - bb * 324;
  const int qi = qr / 18;
  const int qj = qr - qi * 18;
  const int rowBase = bb * 15876 + qi * 7 * 126 + qj * 7;

  const short8 szero = {0, 0, 0, 0, 0, 0, 0, 0};
  const f32x4  fzero = {0.f, 0.f, 0.f, 0.f};

  // ---- stage x window: rows 0..48 real (gathered), 49..63 zero ----
  #pragma unroll
  for (int i = 0; i < 16; ++i) {
    int idx  = tid + i * 256;
    int row  = idx >> 6;
    int colv = idx & 63;
    short8 v = szero;
    if (row < 49) {
      int src = (rowBase + (row / 7) * 126 + (row % 7)) * 512 + colv * 8;
      v = load8(x, src, f32);
    }
    *reinterpret_cast<short8*>(sX + row * 1024 + swz(row, colv * 16u)) = v;
  }
  __syncthreads();

  for (int h = 0; h < 8; ++h) {
    // ---- phase 1: q/k/v projection (waves 0,1,2 -> q,k,v) ----
    if (wid < 3) {
      f32x4 acc[4][4];
      #pragma unroll
      for (int m = 0; m < 4; ++m)
        #pragma unroll
        for (int n = 0; n < 4; ++n) acc[m][n] = fzero;

      for (int k0 = 0; k0 < 16; ++k0) {
        short8 a[4];
        #pragma unroll
        for (int m = 0; m < 4; ++m) {
          uint32_t row = m * 16 + r16;
          a[m] = *reinterpret_cast<const short8*>(
              sX + row * 1024 + swz(row, (uint32_t)(k0 * 64 + hi * 16)));
        }
        #pragma unroll
        for (int n = 0; n < 4; ++n) {
          short8 bfr = load8(wqkv,
              (wid * 512 + h * 64 + n * 16 + r16) * 512 + k0 * 32 + hi * 8, f32);
          #pragma unroll
          for (int m = 0; m < 4; ++m)
            acc[m][n] = MFMA16(a[m], bfr, acc[m][n]);
        }
      }
      char* dst = (wid == 0) ? sQ : (wid == 1) ? sK : sVt;
      const float scale = (wid == 0) ? 0.125f : 1.0f;  // HD^-0.5 on q
      #pragma unroll
      for (int n = 0; n < 4; ++n) {
        int col = n * 16 + r16;
        float bias = ldf(bqkv, wid * 512 + h * 64 + col, f32);
        #pragma unroll
        for (int m = 0; m < 4; ++m) {
          #pragma unroll
          for (int r = 0; r < 4; ++r) {
            int row = m * 16 + hi * 4 + r;
            bf16 bv = __float2bfloat16((acc[m][n][r] + bias) * scale);
            uint32_t off = (wid == 2)
                ? (uint32_t)col * 128u + swz((uint32_t)col, (uint32_t)(row * 2))
                : (uint32_t)row * 128u + swz((uint32_t)row, (uint32_t)(col * 2));
            *reinterpret_cast<bf16*>(dst + off) = bv;
          }
        }
      }
    }
    __syncthreads();

    // ---- phase 2: S = q k^T  (wave w owns m-tile w) ----
    {
      f32x4 sacc[4];
      #pragma unroll
      for (int n = 0; n < 4; ++n) sacc[n] = fzero;
      #pragma unroll
      for (int k0 = 0; k0 < 2; ++k0) {
        uint32_t arow = wid * 16 + r16;
        short8 a = *reinterpret_cast<const short8*>(
            sQ + arow * 128 + swz(arow, (uint32_t)(k0 * 64 + hi * 16)));
        #pragma unroll
        for (int n = 0; n < 4; ++n) {
          uint32_t brow = n * 16 + r16;
          short8 kb = *reinterpret_cast<const short8*>(
              sK + brow * 128 + swz(brow, (uint32_t)(k0 * 64 + hi * 16)));
          sacc[n] = MFMA16(a, kb, sacc[n]);
        }
      }
      #pragma unroll
      for (int n = 0; n < 4; ++n)
        #pragma unroll
        for (int r = 0; r < 4; ++r)
          sS[(wid * 16 + hi * 4 + r) * 65 + n * 16 + r16] = sacc[n][r];
    }
    __syncthreads();

    // ---- phase 3: softmax rows (+RPE); 4 threads per row ----
    {
      int row = tid >> 2;
      int q4  = tid & 3;
      if (row < 49) {
        int j0 = q4 * 13;
        int j1 = (q4 == 3) ? 49 : j0 + 13;
        float mx = -1e30f;
        for (int j = j0; j < j1; ++j) {
          float s = sS[row * 65 + j] + ldf(rpe, relidx[row * 49 + j] * 8 + h, f32);
          sS[row * 65 + j] = s;
          mx = fmaxf(mx, s);
        }
        mx = fmaxf(mx, __shfl_xor(mx, 1));
        mx = fmaxf(mx, __shfl_xor(mx, 2));
        float sum = 0.f;
        for (int j = j0; j < j1; ++j) {
          float e = __expf(sS[row * 65 + j] - mx);
          sS[row * 65 + j] = e;
          sum += e;
        }
        sum += __shfl_xor(sum, 1);
        sum += __shfl_xor(sum, 2);
        float inv = 1.f / sum;
        for (int j = j0; j < j1; ++j)
          *reinterpret_cast<bf16*>(sP + row * 128 + swz((uint32_t)row, (uint32_t)(j * 2))) =
              __float2bfloat16(sS[row * 65 + j] * inv);
        if (q4 == 3)  // zero pad key-columns 49..63 (pad v rows hold bias!)
          for (int j = 49; j < 64; ++j)
            *reinterpret_cast<bf16*>(sP + row * 128 + swz((uint32_t)row, (uint32_t)(j * 2))) =
                __float2bfloat16(0.f);
      } else {
        for (int j = q4 * 16; j < q4 * 16 + 16; ++j)
          *reinterpret_cast<bf16*>(sP + row * 128 + swz((uint32_t)row, (uint32_t)(j * 2))) =
              __float2bfloat16(0.f);
      }
    }
    __syncthreads();

    // ---- phase 4: O = P @ V (wave w owns m-tile w) ----
    {
      f32x4 oacc[4];
      #pragma unroll
      for (int n = 0; n < 4; ++n) oacc[n] = fzero;
      #pragma unroll
      for (int k0 = 0; k0 < 2; ++k0) {
        uint32_t arow = wid * 16 + r16;
        short8 a = *reinterpret_cast<const short8*>(
            sP + arow * 128 + swz(arow, (uint32_t)(k0 * 64 + hi * 16)));
        #pragma unroll
        for (int n = 0; n < 4; ++n) {
          uint32_t brow = n * 16 + r16;  // head-dim index (V stored transposed)
          short8 vb = *reinterpret_cast<const short8*>(
              sVt + brow * 128 + swz(brow, (uint32_t)(k0 * 64 + hi * 16)));
          oacc[n] = MFMA16(a, vb, oacc[n]);
        }
      }
      #pragma unroll
      for (int n = 0; n < 4; ++n) {
        int col = n * 16 + r16;
        #pragma unroll
        for (int r = 0; r < 4; ++r) {
          int row = wid * 16 + hi * 4 + r;
          if (row < 49)
            attn_out[(wi * 49 + row) * 512 + h * 64 + col] =
                __float2bfloat16(oacc[n][r]);
        }
      }
    }
    __syncthreads();
  }
}

// ---------------------------------------------------------------------------
// Kernel 2: out projection (M=64/window, N=512, K=512) + bias + un-permute.
// grid = 2592 windows, block = 256 (4 waves, wave w owns cols [128w,128w+128)).
// Output is ALWAYS f32 (reference output dtype).
// ---------------------------------------------------------------------------
__global__ __launch_bounds__(256) void k_outproj(
    const bf16* __restrict__ attn_in,  // [2592*49, 512] bf16 (ours)
    const void* __restrict__ wo,       // [512, 512]
    const void* __restrict__ bo,       // [512]
    float* __restrict__ out,           // [8*15876, 512] f32
    const int* __restrict__ dflag)
{
  __shared__ __align__(16) char sA[64 * 1024];

  const int f32 = *dflag;  // input-tensor dtype only

  const int tid  = threadIdx.x;
  const int lane = tid & 63;
  const int wid  = tid >> 6;
  const int r16  = lane & 15;
  const int hi   = lane >> 4;
  const int wi   = blockIdx.x;

  const short8 szero = {0, 0, 0, 0, 0, 0, 0, 0};
  const f32x4  fzero = {0.f, 0.f, 0.f, 0.f};

  #pragma unroll
  for (int i = 0; i < 16; ++i) {
    int idx  = tid + i * 256;
    int row  = idx >> 6;
    int colv = idx & 63;
    short8 v = szero;
    if (row < 49)
      v = *reinterpret_cast<const short8*>(attn_in + (wi * 49 + row) * 512 + colv * 8);
    *reinterpret_cast<short8*>(sA + row * 1024 + swz(row, colv * 16u)) = v;
  }
  __syncthreads();

  f32x4 acc[4][8];
  #pragma unroll
  for (int m = 0; m < 4; ++m)
    #pragma unroll
    for (int n = 0; n < 8; ++n) acc[m][n] = fzero;

  for (int k0 = 0; k0 < 16; ++k0) {
    short8 a[4];
    #pragma unroll
    for (int m = 0; m < 4; ++m) {
      uint32_t row = m * 16 + r16;
      a[m] = *reinterpret_cast<const short8*>(
          sA + row * 1024 + swz(row, (uint32_t)(k0 * 64 + hi * 16)));
    }
    #pragma unroll
    for (int n = 0; n < 8; ++n) {
      short8 bfr = load8(wo, (wid * 128 + n * 16 + r16) * 512 + k0 * 32 + hi * 8, f32);
      #pragma unroll
      for (int m = 0; m < 4; ++m)
        acc[m][n] = MFMA16(a[m], bfr, acc[m][n]);
    }
  }
  __syncthreads();  // all waves done reading sA; reuse as bounce buffer

  // bounce: wave-private region [64 rows][128 cols] f32, plain layout
  float* bw = reinterpret_cast<float*>(sA) + wid * 64 * 32;  // 64 rows x 32 f32... (see below)
  // NOTE: 64 KB LDS / 4 waves = 16 KB per wave = 64 rows x 64 f32 BYTES-wise;
  // we need 64 rows x 128 f32 = 32 KB per wave -> doesn't fit as f32.
  // Instead: keep bounce in bf16? No - output must be f32 exact-ish. Use two
  // half-row passes: rows 0..31 then 32..63 (only rows <49 matter).
  // bounce region per wave: 32 rows x 128 f32 = 16 KB.
  (void)bw;

  const int bb = wi / 324;
  const int qr = wi - bb * 324;
  const int qi = qr / 18;
  const int qj = qr - qi * 18;
  const int rowBase = bb * 15876 + qi * 7 * 126 + qj * 7;

  float* bwave = reinterpret_cast<float*>(sA + wid * 16384);  // 32 rows x 128 f32

  #pragma unroll
  for (int half = 0; half < 2; ++half) {
    // stage acc rows [half*32, half*32+32) into bounce as f32
    #pragma unroll
    for (int n = 0; n < 8; ++n) {
      int col = n * 16 + r16;
      float bias = ldf(bo, wid * 128 + col, f32);
      #pragma unroll
      for (int m = half * 2; m < half * 2 + 2; ++m)
        #pragma unroll
        for (int r = 0; r < 4; ++r)
          bwave[(m * 16 + hi * 4 + r - half * 32) * 128 + col] = acc[m][n][r] + bias;
    }
    __syncthreads();

    // scatter rows of this half: 32 rows x 128 cols f32, 4B/lane x 4 elems
    #pragma unroll
    for (int it = 0; it < 16; ++it) {
      int c    = lane + it * 64;          // 0..1023 over 32x(128/4) chunks
      int row  = (c >> 5) + half * 32;    // 32 rows, 32 4-elem chunks each
      int colc = c & 31;
      if (row < 49) {
        f32x4 v = *reinterpret_cast<const f32x4*>(bwave + (row - half * 32) * 128 + colc * 4);
        int dst = (rowBase + (row / 7) * 126 + (row % 7)) * 512 + wid * 128 + colc * 4;
        *reinterpret_cast<f32x4*>(out + dst) = v;
      }
    }
    __syncthreads();
  }
}

extern "C" void kernel_launch(void* const* d_in, const int* in_sizes, int n_in,
                              void* d_out, int out_size, void* d_ws, size_t ws_size,
                              hipStream_t stream) {
  const void* x      = d_in[0];
  const void* wqkv   = d_in[1];
  const void* bqkv   = d_in[2];
  const void* wo     = d_in[3];
  const void* bo     = d_in[4];
  const void* rpe    = d_in[5];
  const int*  relidx = (const int*)d_in[6];

  int*  dflag = (int*)d_ws;                       // ws[0..3]: dtype flag
  bf16* attn  = (bf16*)((char*)d_ws + 256);       // + 2592*49*512*2 bytes

  k_probe<<<dim3(1), dim3(64), 0, stream>>>((const unsigned short*)x, dflag);
  k_win_attn<<<dim3(2592), dim3(256), 0, stream>>>(x, wqkv, bqkv, rpe, relidx, attn, dflag);
  k_outproj<<<dim3(2592), dim3(256), 0, stream>>>(attn, wo, bo, (float*)d_out, dflag);
}

// Round 4
// 1497.591 us; speedup vs baseline: 2.3506x; 2.3506x over previous
//
#include <hip/hip_runtime.h>
#include <hip/hip_bf16.h>
#include <stdint.h>

typedef __attribute__((ext_vector_type(8))) short short8;
typedef __attribute__((ext_vector_type(4))) float f32x4;
typedef __hip_bfloat16 bf16;

#define MFMA16(a, b, c) __builtin_amdgcn_mfma_f32_16x16x32_bf16(a, b, c, 0, 0, 0)

__device__ __forceinline__ uint32_t swz(uint32_t row, uint32_t bir) {
  return bir ^ ((row & 7u) << 4);
}
__device__ __forceinline__ short f2bs(float v) {
  bf16 b = __float2bfloat16(v);
  return *reinterpret_cast<short*>(&b);
}
__device__ __forceinline__ float b2f(bf16 b) { return __bfloat162float(b); }

__device__ __forceinline__ short8 load8(const void* p, int eidx, int f32) {
  short8 r;
  if (f32) {
    const float* f = (const float*)p + eidx;
    f32x4 a = *reinterpret_cast<const f32x4*>(f);
    f32x4 b = *reinterpret_cast<const f32x4*>(f + 4);
    r[0] = f2bs(a[0]); r[1] = f2bs(a[1]); r[2] = f2bs(a[2]); r[3] = f2bs(a[3]);
    r[4] = f2bs(b[0]); r[5] = f2bs(b[1]); r[6] = f2bs(b[2]); r[7] = f2bs(b[3]);
  } else {
    r = *reinterpret_cast<const short8*>((const bf16*)p + eidx);
  }
  return r;
}
__device__ __forceinline__ float ldf(const void* p, int eidx, int f32) {
  return f32 ? ((const float*)p)[eidx] : __bfloat162float(((const bf16*)p)[eidx]);
}

// ---------------------------------------------------------------------------
// Probe: f32 vs bf16 input tensors (see round-2 analysis). 1 => f32.
// ---------------------------------------------------------------------------
__global__ void k_probe(const unsigned short* __restrict__ xu, int* __restrict__ flag) {
  int lane = threadIdx.x;
  int cnt = 0;
  for (int i = lane * 2; i < 4096; i += 128) {
    unsigned short u = xu[i];
    int e = (u >> 7) & 0xFF;
    cnt += (e >= 0x90);
  }
  #pragma unroll
  for (int o = 1; o < 64; o <<= 1) cnt += __shfl_xor(cnt, o);
  if (lane == 0) *flag = (cnt > 100) ? 1 : 0;
}

// ===========================================================================
// FAST PATH (ws >= ~342 MB)
// ===========================================================================

// x -> window-permuted, zero-padded bf16 [2592][64][512]. 4 window-rows/block.
__global__ __launch_bounds__(256) void k_conv_x(
    const void* __restrict__ x, bf16* __restrict__ xwin, const int* __restrict__ dflag)
{
  const int f32 = *dflag;
  int R   = blockIdx.x * 4 + (threadIdx.x >> 6);  // wi*64 + row
  int wi  = R >> 6, row = R & 63;
  int c8  = threadIdx.x & 63;
  short8 v = {0, 0, 0, 0, 0, 0, 0, 0};
  if (row < 49) {
    int bb = wi / 324, qr = wi - bb * 324, qi = qr / 18, qj = qr - qi * 18;
    int rowBase = bb * 15876 + qi * 882 + qj * 7;
    int src = (rowBase + (row / 7) * 126 + row % 7) * 512 + c8 * 8;
    v = load8(x, src, f32);
  }
  *reinterpret_cast<short8*>(xwin + R * 512 + c8 * 8) = v;
}

// weights/bias -> bf16; rpe -> pre-gathered [8][49][64] (cols>=49 zero).
__global__ __launch_bounds__(256) void k_conv_w(
    const void* __restrict__ wqkv, const void* __restrict__ bqkv,
    const void* __restrict__ wo,   const void* __restrict__ bo,
    const void* __restrict__ rpe,  const int* __restrict__ relidx,
    bf16* __restrict__ wqkv_b, bf16* __restrict__ bqkv_b,
    bf16* __restrict__ wo_b,   bf16* __restrict__ bo_b,
    bf16* __restrict__ rpew,   const int* __restrict__ dflag)
{
  const int f32 = *dflag;
  int b = blockIdx.x, t = threadIdx.x;
  if (b < 384) {                       // wqkv: 786432 elems
    int idx = b * 2048 + t * 8;
    short8 v = load8(wqkv, idx, f32);
    *reinterpret_cast<short8*>(wqkv_b + idx) = v;
  } else if (b < 512) {                // wo: 262144 elems
    int idx = (b - 384) * 2048 + t * 8;
    short8 v = load8(wo, idx, f32);
    *reinterpret_cast<short8*>(wo_b + idx) = v;
  } else if (b == 512) {               // biases
    for (int j = t; j < 1536; j += 256) {
      bf16 bb = __float2bfloat16(ldf(bqkv, j, f32));
      bqkv_b[j] = bb;
    }
    for (int j = t; j < 512; j += 256) {
      bf16 bb = __float2bfloat16(ldf(bo, j, f32));
      bo_b[j] = bb;
    }
  } else {                             // rpew head h = b-513: [49][64]
    int h = b - 513;
    for (int e = t; e < 3136; e += 256) {
      int q = e >> 6, c = e & 63;
      float v = (c < 49) ? ldf(rpe, relidx[q * 49 + c] * 8 + h, f32) : 0.f;
      rpew[h * 3136 + e] = __float2bfloat16(v);
    }
  }
}

// Fused per-(window,head): QKV proj -> 1 barrier -> QK^T -> in-reg softmax -> PV.
// grid 20736 (XCD-chunked), block 256 (4 waves), LDS 32 KB.
__global__ __launch_bounds__(256) void k_fused(
    const bf16* __restrict__ xwin,   // [2592][64][512]
    const bf16* __restrict__ wqkv_b, // [1536][512]
    const bf16* __restrict__ bqkv_b, // [1536]
    const bf16* __restrict__ rpew,   // [8][49][64]
    bf16* __restrict__ attn)         // [2592][64][512], pad rows never written
{
  __shared__ __align__(16) char sQ[64 * 128];
  __shared__ __align__(16) char sK[64 * 128];
  __shared__ __align__(16) char sVt[64 * 128];
  __shared__ __align__(16) char sP[4 * 16 * 128];  // per-wave [16][64]

  const int tid = threadIdx.x, lane = tid & 63, w = tid >> 6;
  const int r16 = lane & 15, hi = lane >> 4;

  // XCD-chunked: 20736 = 8*2592; same-window head-blocks land on one XCD.
  int b  = blockIdx.x;
  int g  = (b & 7) * 2592 + (b >> 3);
  int wi = g >> 3, h = g & 7;

  const f32x4 fzero = {0.f, 0.f, 0.f, 0.f};

  // ---- QKV projection: wave w owns n-tile w (cols w*16..) of q,k,v ----
  f32x4 acc[3][4];
  #pragma unroll
  for (int t = 0; t < 3; ++t)
    #pragma unroll
    for (int m = 0; m < 4; ++m) acc[t][m] = fzero;

  const bf16* xbase = xwin + wi * 64 * 512;
  for (int k0 = 0; k0 < 16; ++k0) {
    short8 a[4];
    #pragma unroll
    for (int m = 0; m < 4; ++m)
      a[m] = *reinterpret_cast<const short8*>(xbase + (m * 16 + r16) * 512 + k0 * 32 + hi * 8);
    #pragma unroll
    for (int t = 0; t < 3; ++t) {
      short8 bb = *reinterpret_cast<const short8*>(
          wqkv_b + (t * 512 + h * 64 + w * 16 + r16) * 512 + k0 * 32 + hi * 8);
      #pragma unroll
      for (int m = 0; m < 4; ++m)
        acc[t][m] = MFMA16(a[m], bb, acc[t][m]);
    }
  }

  // epilogue: bias (+0.125 scale on q), write LDS (Q,K row-major; V transposed)
  {
    int d = w * 16 + r16;
    float bq = b2f(bqkv_b[h * 64 + d]);
    float bk = b2f(bqkv_b[512 + h * 64 + d]);
    float bv = b2f(bqkv_b[1024 + h * 64 + d]);
    #pragma unroll
    for (int m = 0; m < 4; ++m)
      #pragma unroll
      for (int r = 0; r < 4; ++r) {
        int row = m * 16 + hi * 4 + r;
        *reinterpret_cast<bf16*>(sQ + row * 128 + swz(row, 2 * d)) =
            __float2bfloat16((acc[0][m][r] + bq) * 0.125f);
        *reinterpret_cast<bf16*>(sK + row * 128 + swz(row, 2 * d)) =
            __float2bfloat16(acc[1][m][r] + bk);
        *reinterpret_cast<bf16*>(sVt + d * 128 + swz(d, 2 * row)) =
            __float2bfloat16(acc[2][m][r] + bv);
      }
  }
  __syncthreads();  // the only block-wide barrier

  // ---- S = q k^T for wave's 16 q-rows ----
  f32x4 s[4];
  #pragma unroll
  for (int n = 0; n < 4; ++n) s[n] = fzero;
  #pragma unroll
  for (int k0 = 0; k0 < 2; ++k0) {
    int qrow = w * 16 + r16;
    short8 a = *reinterpret_cast<const short8*>(
        sQ + qrow * 128 + swz(qrow, k0 * 64 + hi * 16));
    #pragma unroll
    for (int n = 0; n < 4; ++n) {
      int krow = n * 16 + r16;
      short8 kb = *reinterpret_cast<const short8*>(
          sK + krow * 128 + swz(krow, k0 * 64 + hi * 16));
      s[n] = MFMA16(a, kb, s[n]);
    }
  }

  // ---- +RPE, mask cols>=49, in-register softmax ----
  // lane holds S[qrow = w*16+hi*4+rr][col = n*16+r16]
  #pragma unroll
  for (int n = 0; n < 4; ++n) {
    int col = n * 16 + r16;
    #pragma unroll
    for (int rr = 0; rr < 4; ++rr) {
      int qrow = w * 16 + hi * 4 + rr;
      int qc = qrow < 49 ? qrow : 48;
      float sv = s[n][rr] + b2f(rpew[h * 3136 + qc * 64 + col]);
      if (col >= 49) sv = -1e30f;
      s[n][rr] = sv;
    }
  }
  #pragma unroll
  for (int rr = 0; rr < 4; ++rr) {
    float mx = fmaxf(fmaxf(s[0][rr], s[1][rr]), fmaxf(s[2][rr], s[3][rr]));
    mx = fmaxf(mx, __shfl_xor(mx, 1));
    mx = fmaxf(mx, __shfl_xor(mx, 2));
    mx = fmaxf(mx, __shfl_xor(mx, 4));
    mx = fmaxf(mx, __shfl_xor(mx, 8));
    float su = 0.f;
    #pragma unroll
    for (int n = 0; n < 4; ++n) {
      float e = __expf(s[n][rr] - mx);
      s[n][rr] = e;
      su += e;
    }
    su += __shfl_xor(su, 1);
    su += __shfl_xor(su, 2);
    su += __shfl_xor(su, 4);
    su += __shfl_xor(su, 8);
    float inv = 1.f / su;
    #pragma unroll
    for (int n = 0; n < 4; ++n) s[n][rr] *= inv;
  }

  // ---- P -> wave-private LDS slab (transpose to A-frag layout) ----
  char* pw = sP + w * 2048;
  #pragma unroll
  for (int n = 0; n < 4; ++n)
    #pragma unroll
    for (int rr = 0; rr < 4; ++rr) {
      int rl = hi * 4 + rr, col = n * 16 + r16;
      *reinterpret_cast<bf16*>(pw + rl * 128 + swz(rl, 2 * col)) =
          __float2bfloat16(s[n][rr]);
    }
  // wave-private region: no block barrier needed; compiler orders ds ops.

  // ---- O = P @ V ----
  f32x4 o[4];
  #pragma unroll
  for (int n = 0; n < 4; ++n) o[n] = fzero;
  #pragma unroll
  for (int k0 = 0; k0 < 2; ++k0) {
    short8 a = *reinterpret_cast<const short8*>(
        pw + r16 * 128 + swz(r16, k0 * 64 + hi * 16));
    #pragma unroll
    for (int n = 0; n < 4; ++n) {
      int d = n * 16 + r16;
      short8 vb = *reinterpret_cast<const short8*>(
          sVt + d * 128 + swz(d, k0 * 64 + hi * 16));
      o[n] = MFMA16(a, vb, o[n]);
    }
  }
  #pragma unroll
  for (int n = 0; n < 4; ++n)
    #pragma unroll
    for (int r = 0; r < 4; ++r) {
      int row = w * 16 + hi * 4 + r;
      if (row < 49)
        attn[(wi * 64 + row) * 512 + h * 64 + n * 16 + r16] =
            __float2bfloat16(o[n][r]);
    }
}

// out projection (fast): bf16 weights, padded attn input, f32 output.
__global__ __launch_bounds__(256) void k_outproj_fast(
    const bf16* __restrict__ attn_in,  // [2592][64][512]
    const bf16* __restrict__ wo_b,     // [512][512]
    const bf16* __restrict__ bo_b,     // [512]
    float* __restrict__ out)           // [8*15876][512] f32
{
  __shared__ __align__(16) char sA[64 * 1024];

  const int tid = threadIdx.x, lane = tid & 63, wid = tid >> 6;
  const int r16 = lane & 15, hi = lane >> 4;
  const int wi  = blockIdx.x;
  const f32x4 fzero = {0.f, 0.f, 0.f, 0.f};

  #pragma unroll
  for (int i = 0; i < 16; ++i) {
    int idx = tid + i * 256;
    int row = idx >> 6, colv = idx & 63;
    short8 v = *reinterpret_cast<const short8*>(attn_in + (wi * 64 + row) * 512 + colv * 8);
    *reinterpret_cast<short8*>(sA + row * 1024 + swz(row, colv * 16u)) = v;
  }
  __syncthreads();

  f32x4 acc[4][8];
  #pragma unroll
  for (int m = 0; m < 4; ++m)
    #pragma unroll
    for (int n = 0; n < 8; ++n) acc[m][n] = fzero;

  for (int k0 = 0; k0 < 16; ++k0) {
    short8 a[4];
    #pragma unroll
    for (int m = 0; m < 4; ++m) {
      uint32_t row = m * 16 + r16;
      a[m] = *reinterpret_cast<const short8*>(
          sA + row * 1024 + swz(row, (uint32_t)(k0 * 64 + hi * 16)));
    }
    #pragma unroll
    for (int n = 0; n < 8; ++n) {
      short8 bfr = *reinterpret_cast<const short8*>(
          wo_b + (wid * 128 + n * 16 + r16) * 512 + k0 * 32 + hi * 8);
      #pragma unroll
      for (int m = 0; m < 4; ++m)
        acc[m][n] = MFMA16(a[m], bfr, acc[m][n]);
    }
  }
  __syncthreads();

  const int bb = wi / 324, qr = wi - bb * 324, qi = qr / 18, qj = qr - qi * 18;
  const int rowBase = bb * 15876 + qi * 882 + qj * 7;

  float* bwave = reinterpret_cast<float*>(sA + wid * 16384);  // 32 rows x 128 f32

  #pragma unroll
  for (int half = 0; half < 2; ++half) {
    #pragma unroll
    for (int n = 0; n < 8; ++n) {
      int col = n * 16 + r16;
      float bias = b2f(bo_b[wid * 128 + col]);
      #pragma unroll
      for (int m = half * 2; m < half * 2 + 2; ++m)
        #pragma unroll
        for (int r = 0; r < 4; ++r)
          bwave[(m * 16 + hi * 4 + r - half * 32) * 128 + col] = acc[m][n][r] + bias;
    }
    __syncthreads();
    #pragma unroll
    for (int it = 0; it < 16; ++it) {
      int c = lane + it * 64;
      int row = (c >> 5) + half * 32;
      int colc = c & 31;
      if (row < 49) {
        f32x4 v = *reinterpret_cast<const f32x4*>(bwave + (row - half * 32) * 128 + colc * 4);
        int dst = (rowBase + (row / 7) * 126 + (row % 7)) * 512 + wid * 128 + colc * 4;
        *reinterpret_cast<f32x4*>(out + dst) = v;
      }
    }
    __syncthreads();
  }
}

// ===========================================================================
// FALLBACK PATH (round-3 kernels, verbatim) — used when ws is too small.
// ===========================================================================
__global__ __launch_bounds__(256) void k_win_attn(
    const void* __restrict__ x, const void* __restrict__ wqkv,
    const void* __restrict__ bqkv, const void* __restrict__ rpe,
    const int* __restrict__ relidx, bf16* __restrict__ attn_out,
    const int* __restrict__ dflag)
{
  __shared__ __align__(16) char sX[64 * 1024];
  __shared__ __align__(16) char sQ[64 * 128];
  __shared__ __align__(16) char sK[64 * 128];
  __shared__ __align__(16) char sVt[64 * 128];
  __shared__ float sS[64 * 65];
  __shared__ __align__(16) char sP[64 * 128];

  const int f32 = *dflag;
  const int tid = threadIdx.x, lane = tid & 63, wid = tid >> 6;
  const int r16 = lane & 15, hi = lane >> 4;
  const int wi = blockIdx.x;
  const int bb = wi / 324, qr = wi - bb * 324, qi = qr / 18, qj = qr - qi * 18;
  const int rowBase = bb * 15876 + qi * 882 + qj * 7;
  const short8 szero = {0, 0, 0, 0, 0, 0, 0, 0};
  const f32x4 fzero = {0.f, 0.f, 0.f, 0.f};

  #pragma unroll
  for (int i = 0; i < 16; ++i) {
    int idx = tid + i * 256;
    int row = idx >> 6, colv = idx & 63;
    short8 v = szero;
    if (row < 49) {
      int src = (rowBase + (row / 7) * 126 + (row % 7)) * 512 + colv * 8;
      v = load8(x, src, f32);
    }
    *reinterpret_cast<short8*>(sX + row * 1024 + swz(row, colv * 16u)) = v;
  }
  __syncthreads();

  for (int h = 0; h < 8; ++h) {
    if (wid < 3) {
      f32x4 acc[4][4];
      #pragma unroll
      for (int m = 0; m < 4; ++m)
        #pragma unroll
        for (int n = 0; n < 4; ++n) acc[m][n] = fzero;
      for (int k0 = 0; k0 < 16; ++k0) {
        short8 a[4];
        #pragma unroll
        for (int m = 0; m < 4; ++m) {
          uint32_t row = m * 16 + r16;
          a[m] = *reinterpret_cast<const short8*>(
              sX + row * 1024 + swz(row, (uint32_t)(k0 * 64 + hi * 16)));
        }
        #pragma unroll
        for (int n = 0; n < 4; ++n) {
          short8 bfr = load8(wqkv,
              (wid * 512 + h * 64 + n * 16 + r16) * 512 + k0 * 32 + hi * 8, f32);
          #pragma unroll
          for (int m = 0; m < 4; ++m)
            acc[m][n] = MFMA16(a[m], bfr, acc[m][n]);
        }
      }
      char* dst = (wid == 0) ? sQ : (wid == 1) ? sK : sVt;
      const float scale = (wid == 0) ? 0.125f : 1.0f;
      #pragma unroll
      for (int n = 0; n < 4; ++n) {
        int col = n * 16 + r16;
        float bias = ldf(bqkv, wid * 512 + h * 64 + col, f32);
        #pragma unroll
        for (int m = 0; m < 4; ++m)
          #pragma unroll
          for (int r = 0; r < 4; ++r) {
            int row = m * 16 + hi * 4 + r;
            bf16 bv = __float2bfloat16((acc[m][n][r] + bias) * scale);
            uint32_t off = (wid == 2)
                ? (uint32_t)col * 128u + swz((uint32_t)col, (uint32_t)(row * 2))
                : (uint32_t)row * 128u + swz((uint32_t)row, (uint32_t)(col * 2));
            *reinterpret_cast<bf16*>(dst + off) = bv;
          }
      }
    }
    __syncthreads();
    {
      f32x4 sacc[4];
      #pragma unroll
      for (int n = 0; n < 4; ++n) sacc[n] = fzero;
      #pragma unroll
      for (int k0 = 0; k0 < 2; ++k0) {
        uint32_t arow = wid * 16 + r16;
        short8 a = *reinterpret_cast<const short8*>(
            sQ + arow * 128 + swz(arow, (uint32_t)(k0 * 64 + hi * 16)));
        #pragma unroll
        for (int n = 0; n < 4; ++n) {
          uint32_t brow = n * 16 + r16;
          short8 kb = *reinterpret_cast<const short8*>(
              sK + brow * 128 + swz(brow, (uint32_t)(k0 * 64 + hi * 16)));
          sacc[n] = MFMA16(a, kb, sacc[n]);
        }
      }
      #pragma unroll
      for (int n = 0; n < 4; ++n)
        #pragma unroll
        for (int r = 0; r < 4; ++r)
          sS[(wid * 16 + hi * 4 + r) * 65 + n * 16 + r16] = sacc[n][r];
    }
    __syncthreads();
    {
      int row = tid >> 2, q4 = tid & 3;
      if (row < 49) {
        int j0 = q4 * 13, j1 = (q4 == 3) ? 49 : j0 + 13;
        float mx = -1e30f;
        for (int j = j0; j < j1; ++j) {
          float s = sS[row * 65 + j] + ldf(rpe, relidx[row * 49 + j] * 8 + h, f32);
          sS[row * 65 + j] = s;
          mx = fmaxf(mx, s);
        }
        mx = fmaxf(mx, __shfl_xor(mx, 1));
        mx = fmaxf(mx, __shfl_xor(mx, 2));
        float sum = 0.f;
        for (int j = j0; j < j1; ++j) {
          float e = __expf(sS[row * 65 + j] - mx);
          sS[row * 65 + j] = e;
          sum += e;
        }
        sum += __shfl_xor(sum, 1);
        sum += __shfl_xor(sum, 2);
        float inv = 1.f / sum;
        for (int j = j0; j < j1; ++j)
          *reinterpret_cast<bf16*>(sP + row * 128 + swz((uint32_t)row, (uint32_t)(j * 2))) =
              __float2bfloat16(sS[row * 65 + j] * inv);
        if (q4 == 3)
          for (int j = 49; j < 64; ++j)
            *reinterpret_cast<bf16*>(sP + row * 128 + swz((uint32_t)row, (uint32_t)(j * 2))) =
                __float2bfloat16(0.f);
      } else {
        for (int j = q4 * 16; j < q4 * 16 + 16; ++j)
          *reinterpret_cast<bf16*>(sP + row * 128 + swz((uint32_t)row, (uint32_t)(j * 2))) =
              __float2bfloat16(0.f);
      }
    }
    __syncthreads();
    {
      f32x4 oacc[4];
      #pragma unroll
      for (int n = 0; n < 4; ++n) oacc[n] = fzero;
      #pragma unroll
      for (int k0 = 0; k0 < 2; ++k0) {
        uint32_t arow = wid * 16 + r16;
        short8 a = *reinterpret_cast<const short8*>(
            sP + arow * 128 + swz(arow, (uint32_t)(k0 * 64 + hi * 16)));
        #pragma unroll
        for (int n = 0; n < 4; ++n) {
          uint32_t brow = n * 16 + r16;
          short8 vb = *reinterpret_cast<const short8*>(
              sVt + brow * 128 + swz(brow, (uint32_t)(k0 * 64 + hi * 16)));
          oacc[n] = MFMA16(a, vb, oacc[n]);
        }
      }
      #pragma unroll
      for (int n = 0; n < 4; ++n)
        #pragma unroll
        for (int r = 0; r < 4; ++r) {
          int row = wid * 16 + hi * 4 + r;
          if (row < 49)
            attn_out[(wi * 49 + row) * 512 + h * 64 + n * 16 + r16] =
                __float2bfloat16(oacc[n][r]);
        }
    }
    __syncthreads();
  }
}

__global__ __launch_bounds__(256) void k_outproj_slow(
    const bf16* __restrict__ attn_in, const void* __restrict__ wo,
    const void* __restrict__ bo, float* __restrict__ out,
    const int* __restrict__ dflag)
{
  __shared__ __align__(16) char sA[64 * 1024];
  const int f32 = *dflag;
  const int tid = threadIdx.x, lane = tid & 63, wid = tid >> 6;
  const int r16 = lane & 15, hi = lane >> 4;
  const int wi = blockIdx.x;
  const short8 szero = {0, 0, 0, 0, 0, 0, 0, 0};
  const f32x4 fzero = {0.f, 0.f, 0.f, 0.f};

  #pragma unroll
  for (int i = 0; i < 16; ++i) {
    int idx = tid + i * 256;
    int row = idx >> 6, colv = idx & 63;
    short8 v = szero;
    if (row < 49)
      v = *reinterpret_cast<const short8*>(attn_in + (wi * 49 + row) * 512 + colv * 8);
    *reinterpret_cast<short8*>(sA + row * 1024 + swz(row, colv * 16u)) = v;
  }
  __syncthreads();

  f32x4 acc[4][8];
  #pragma unroll
  for (int m = 0; m < 4; ++m)
    #pragma unroll
    for (int n = 0; n < 8; ++n) acc[m][n] = fzero;

  for (int k0 = 0; k0 < 16; ++k0) {
    short8 a[4];
    #pragma unroll
    for (int m = 0; m < 4; ++m) {
      uint32_t row = m * 16 + r16;
      a[m] = *reinterpret_cast<const short8*>(
          sA + row * 1024 + swz(row, (uint32_t)(k0 * 64 + hi * 16)));
    }
    #pragma unroll
    for (int n = 0; n < 8; ++n) {
      short8 bfr = load8(wo, (wid * 128 + n * 16 + r16) * 512 + k0 * 32 + hi * 8, f32);
      #pragma unroll
      for (int m = 0; m < 4; ++m)
        acc[m][n] = MFMA16(a[m], bfr, acc[m][n]);
    }
  }
  __syncthreads();

  const int bb = wi / 324, qr = wi - bb * 324, qi = qr / 18, qj = qr - qi * 18;
  const int rowBase = bb * 15876 + qi * 882 + qj * 7;
  float* bwave = reinterpret_cast<float*>(sA + wid * 16384);

  #pragma unroll
  for (int half = 0; half < 2; ++half) {
    #pragma unroll
    for (int n = 0; n < 8; ++n) {
      int col = n * 16 + r16;
      float bias = ldf(bo, wid * 128 + col, f32);
      #pragma unroll
      for (int m = half * 2; m < half * 2 + 2; ++m)
        #pragma unroll
        for (int r = 0; r < 4; ++r)
          bwave[(m * 16 + hi * 4 + r - half * 32) * 128 + col] = acc[m][n][r] + bias;
    }
    __syncthreads();
    #pragma unroll
    for (int it = 0; it < 16; ++it) {
      int c = lane + it * 64;
      int row = (c >> 5) + half * 32;
      int colc = c & 31;
      if (row < 49) {
        f32x4 v = *reinterpret_cast<const f32x4*>(bwave + (row - half * 32) * 128 + colc * 4);
        int dst = (rowBase + (row / 7) * 126 + (row % 7)) * 512 + wid * 128 + colc * 4;
        *reinterpret_cast<f32x4*>(out + dst) = v;
      }
    }
    __syncthreads();
  }
}

extern "C" void kernel_launch(void* const* d_in, const int* in_sizes, int n_in,
                              void* d_out, int out_size, void* d_ws, size_t ws_size,
                              hipStream_t stream) {
  const void* x      = d_in[0];
  const void* wqkv   = d_in[1];
  const void* bqkv   = d_in[2];
  const void* wo     = d_in[3];
  const void* bo     = d_in[4];
  const void* rpe    = d_in[5];
  const int*  relidx = (const int*)d_in[6];

  char* ws = (char*)d_ws;
  int* dflag = (int*)ws;

  // fast-path workspace layout (all offsets 256-aligned)
  const size_t OFF_XWIN = 256;
  const size_t SZ_XWIN  = 2592ull * 64 * 512 * 2;            // 169,869,312
  const size_t OFF_WQKV = OFF_XWIN + SZ_XWIN;
  const size_t OFF_WO   = OFF_WQKV + 1536ull * 512 * 2;
  const size_t OFF_BQKV = OFF_WO + 512ull * 512 * 2;
  const size_t OFF_BO   = OFF_BQKV + 3072;
  const size_t OFF_RPEW = OFF_BO + 1024;
  const size_t OFF_ATTN = OFF_RPEW + 8ull * 3136 * 2;
  const size_t TOTAL    = OFF_ATTN + SZ_XWIN;                // ~341.9 MB

  k_probe<<<dim3(1), dim3(64), 0, stream>>>((const unsigned short*)x, dflag);

  if (ws_size >= TOTAL) {
    bf16* xwin   = (bf16*)(ws + OFF_XWIN);
    bf16* wqkv_b = (bf16*)(ws + OFF_WQKV);
    bf16* wo_b   = (bf16*)(ws + OFF_WO);
    bf16* bqkv_b = (bf16*)(ws + OFF_BQKV);
    bf16* bo_b   = (bf16*)(ws + OFF_BO);
    bf16* rpew   = (bf16*)(ws + OFF_RPEW);
    bf16* attn   = (bf16*)(ws + OFF_ATTN);

    k_conv_x<<<dim3(41472), dim3(256), 0, stream>>>(x, xwin, dflag);
    k_conv_w<<<dim3(521), dim3(256), 0, stream>>>(wqkv, bqkv, wo, bo, rpe, relidx,
                                                  wqkv_b, bqkv_b, wo_b, bo_b, rpew, dflag);
    k_fused<<<dim3(20736), dim3(256), 0, stream>>>(xwin, wqkv_b, bqkv_b, rpew, attn);
    k_outproj_fast<<<dim3(2592), dim3(256), 0, stream>>>(attn, wo_b, bo_b, (float*)d_out);
  } else {
    bf16* attn = (bf16*)(ws + 256);  // 130 MB
    k_win_attn<<<dim3(2592), dim3(256), 0, stream>>>(x, wqkv, bqkv, rpe, relidx, attn, dflag);
    k_outproj_slow<<<dim3(2592), dim3(256), 0, stream>>>(attn, wo, bo, (float*)d_out, dflag);
  }
}

// Round 5
// 903.799 us; speedup vs baseline: 3.8950x; 1.6570x over previous
//
#include <hip/hip_runtime.h>
#include <hip/hip_bf16.h>
#include <stdint.h>

typedef __attribute__((ext_vector_type(8))) short short8;
typedef __attribute__((ext_vector_type(4))) float f32x4;
typedef __hip_bfloat16 bf16;

#define MFMA16(a, b, c) __builtin_amdgcn_mfma_f32_16x16x32_bf16(a, b, c, 0, 0, 0)

// XOR swizzle: permutes 16B groups within each 128B sub-block by row&7.
__device__ __forceinline__ uint32_t swz(uint32_t row, uint32_t bir) {
  return bir ^ ((row & 7u) << 4);
}
__device__ __forceinline__ short f2bs(float v) {
  bf16 b = __float2bfloat16(v);
  return *reinterpret_cast<short*>(&b);
}
__device__ __forceinline__ float b2f(bf16 b) { return __bfloat162float(b); }

__device__ __forceinline__ short8 load8(const void* p, long eidx, int f32) {
  short8 r;
  if (f32) {
    const float* f = (const float*)p + eidx;
    f32x4 a = *reinterpret_cast<const f32x4*>(f);
    f32x4 b = *reinterpret_cast<const f32x4*>(f + 4);
    r[0] = f2bs(a[0]); r[1] = f2bs(a[1]); r[2] = f2bs(a[2]); r[3] = f2bs(a[3]);
    r[4] = f2bs(b[0]); r[5] = f2bs(b[1]); r[6] = f2bs(b[2]); r[7] = f2bs(b[3]);
  } else {
    r = *reinterpret_cast<const short8*>((const bf16*)p + eidx);
  }
  return r;
}
__device__ __forceinline__ float ldf(const void* p, long eidx, int f32) {
  return f32 ? ((const float*)p)[eidx] : __bfloat162float(((const bf16*)p)[eidx]);
}

// async global->LDS, 16B per lane. LDS dest = uniform base + lane*16 (HW rule).
__device__ __forceinline__ void gl_lds16(const void* g, void* l) {
  __builtin_amdgcn_global_load_lds(
      (const __attribute__((address_space(1))) unsigned int*)g,
      (__attribute__((address_space(3))) unsigned int*)l, 16, 0, 0);
}

// ---------------------------------------------------------------------------
// Probe: f32 vs bf16 input tensors (round-2 analysis; confirmed f32). 1 => f32.
// ---------------------------------------------------------------------------
__global__ void k_probe(const unsigned short* __restrict__ xu, int* __restrict__ flag) {
  int lane = threadIdx.x;
  int cnt = 0;
  for (int i = lane * 2; i < 4096; i += 128) {
    unsigned short u = xu[i];
    int e = (u >> 7) & 0xFF;
    cnt += (e >= 0x90);
  }
  #pragma unroll
  for (int o = 1; o < 64; o <<= 1) cnt += __shfl_xor(cnt, o);
  if (lane == 0) *flag = (cnt > 100) ? 1 : 0;
}

// ---------------------------------------------------------------------------
// conv_x: x f32 -> window-permuted, zero-padded, SWIZZLED bf16 blob
// [165888 rows][1024 B], byte = R*1024 + (c8*16 ^ ((R&7)<<4)).
// ---------------------------------------------------------------------------
__global__ __launch_bounds__(256) void k_conv_x2(
    const void* __restrict__ x, char* __restrict__ xblob, const int* __restrict__ dflag)
{
  const int f32 = *dflag;
  int R  = blockIdx.x * 4 + (threadIdx.x >> 6);  // global padded row
  int wi = R >> 6, row = R & 63;
  int c8 = threadIdx.x & 63;
  short8 v = {0, 0, 0, 0, 0, 0, 0, 0};
  if (row < 49) {
    int bb = wi / 324, qr = wi - bb * 324, qi = qr / 18, qj = qr - qi * 18;
    int rowBase = bb * 15876 + qi * 882 + qj * 7;
    long src = (long)(rowBase + (row / 7) * 126 + row % 7) * 512 + c8 * 8;
    v = load8(x, src, f32);
  }
  *reinterpret_cast<short8*>(xblob + (size_t)R * 1024 + ((uint32_t)(c8 * 16) ^ ((R & 7u) << 4))) = v;
}

// ---------------------------------------------------------------------------
// conv_w: weights -> swizzled bf16 blobs; biases -> bf16; rpe pre-gathered.
// ---------------------------------------------------------------------------
__global__ __launch_bounds__(256) void k_conv_w2(
    const void* __restrict__ wqkv, const void* __restrict__ bqkv,
    const void* __restrict__ wo,   const void* __restrict__ bo,
    const void* __restrict__ rpe,  const int* __restrict__ relidx,
    char* __restrict__ wqkvb, bf16* __restrict__ bqkvb,
    char* __restrict__ wob,   bf16* __restrict__ bob,
    bf16* __restrict__ rpew,  const int* __restrict__ dflag)
{
  const int f32 = *dflag;
  int b = blockIdx.x, t = threadIdx.x;
  if (b < 384) {                       // wqkv: 1536x512
    long idx = (long)b * 2048 + t * 8;
    int row = (int)(idx >> 9);
    uint32_t g = ((uint32_t)idx & 511u) >> 3;
    short8 v = load8(wqkv, idx, f32);
    *reinterpret_cast<short8*>(wqkvb + (size_t)row * 1024 + ((g * 16) ^ ((row & 7u) << 4))) = v;
  } else if (b < 512) {                // wo: 512x512
    long idx = (long)(b - 384) * 2048 + t * 8;
    int row = (int)(idx >> 9);
    uint32_t g = ((uint32_t)idx & 511u) >> 3;
    short8 v = load8(wo, idx, f32);
    *reinterpret_cast<short8*>(wob + (size_t)row * 1024 + ((g * 16) ^ ((row & 7u) << 4))) = v;
  } else if (b == 512) {               // biases
    for (int j = t; j < 1536; j += 256) bqkvb[j] = __float2bfloat16(ldf(bqkv, j, f32));
    for (int j = t; j < 512;  j += 256) bob[j]  = __float2bfloat16(ldf(bo, j, f32));
  } else {                             // rpew head h: [49 padded to 64 q][64 cols]
    int h = b - 513;
    for (int e = t; e < 3136; e += 256) {
      int q = e >> 6, c = e & 63;
      float v = (c < 49) ? ldf(rpe, (long)relidx[q * 49 + c] * 8 + h, f32) : 0.f;
      rpew[h * 3136 + e] = __float2bfloat16(v);
    }
  }
}

// ---------------------------------------------------------------------------
// k_qkv_gemm: C[rows 128][1536-slice 128] = xwin @ wqkv^T (m97 structure).
// grid = 324 (mb) x 12 (nb) per chunk; block 256 / 4 waves; LDS 32 KB.
// Epilogue -> per-(window,head) 64x64 tiles: q,k swizzled; v linear; bias;
// q scaled by 0.125.
// ---------------------------------------------------------------------------
__global__ __launch_bounds__(256) void k_qkv_gemm(
    const char* __restrict__ xblob,   // [165888][1024B] swizzled
    const char* __restrict__ wqkvb,   // [1536][1024B] swizzled
    const bf16* __restrict__ bqkvb,   // [1536]
    bf16* __restrict__ qkv,           // [3][648][8][4096] elems (chunk-local)
    int row0)                         // first global row of this chunk
{
  __shared__ __align__(16) char sA[16384];
  __shared__ __align__(16) char sB[16384];

  const int tid = threadIdx.x, lane = tid & 63, w = tid >> 6;
  const int r16 = lane & 15, hi = lane >> 4;
  const int mb = blockIdx.x % 324, nb = blockIdx.x / 324;

  const f32x4 fzero = {0.f, 0.f, 0.f, 0.f};
  f32x4 acc[4][4];
  #pragma unroll
  for (int m = 0; m < 4; ++m)
    #pragma unroll
    for (int n = 0; n < 4; ++n) acc[m][n] = fzero;

  const char* Abase = xblob + (size_t)(row0 + mb * 128) * 1024;
  const char* Bbase = wqkvb + (size_t)nb * 131072;

  for (int k0 = 0; k0 < 8; ++k0) {
    if (k0) __syncthreads();
    #pragma unroll
    for (int j = 0; j < 8; ++j) {
      int ch = w * 8 + j;
      if (ch < 16) {
        gl_lds16(Abase + (size_t)(ch * 8 + (lane >> 3)) * 1024 + k0 * 128 + (lane & 7) * 16,
                 sA + ch * 1024);
      } else {
        int c2 = ch - 16;
        gl_lds16(Bbase + (size_t)(c2 * 8 + (lane >> 3)) * 1024 + k0 * 128 + (lane & 7) * 16,
                 sB + c2 * 1024);
      }
    }
    __syncthreads();

    #pragma unroll
    for (int ks = 0; ks < 2; ++ks) {
      uint32_t cb = (uint32_t)((ks * 4 + hi) * 16) ^ ((r16 & 7u) << 4);
      short8 aF[4], bF[4];
      #pragma unroll
      for (int m = 0; m < 4; ++m)
        aF[m] = *reinterpret_cast<const short8*>(sA + ((w & 1) * 64 + m * 16 + r16) * 128 + cb);
      #pragma unroll
      for (int n = 0; n < 4; ++n)
        bF[n] = *reinterpret_cast<const short8*>(sB + ((w >> 1) * 64 + n * 16 + r16) * 128 + cb);
      #pragma unroll
      for (int m = 0; m < 4; ++m)
        #pragma unroll
        for (int n = 0; n < 4; ++n)
          acc[m][n] = MFMA16(aF[m], bF[n], acc[m][n]);
    }
  }

  // epilogue: wave quadrant rows (w&1)*64, cols (w>>1)*64 -> one (t,h) tile
  const int cgb = nb * 128 + (w >> 1) * 64;   // 64-aligned col base
  const int t   = cgb >> 9;
  const int h   = (cgb >> 6) & 7;
  const int wiL = mb * 2 + (w & 1);           // chunk-local window
  bf16* tile = qkv + ((size_t)(t * 648 + wiL) * 8 + h) * 4096;
  const float scale = (t == 0) ? 0.125f : 1.0f;

  #pragma unroll
  for (int n = 0; n < 4; ++n) {
    int d = n * 16 + r16;
    float bias = b2f(bqkvb[cgb + d]);
    #pragma unroll
    for (int m = 0; m < 4; ++m)
      #pragma unroll
      for (int r = 0; r < 4; ++r) {
        int row = m * 16 + hi * 4 + r;
        bf16 v = __float2bfloat16((acc[m][n][r] + bias) * scale);
        if (t < 2)
          *reinterpret_cast<bf16*>((char*)tile + row * 128 + ((uint32_t)(2 * d) ^ ((row & 7u) << 4))) = v;
        else
          tile[row * 64 + d] = v;
      }
  }
}

// ---------------------------------------------------------------------------
// k_attn2: per (window, head). Stage q/k/v tiles (linear 8KB copies) ->
// QK^T -> in-reg softmax(+RPE, mask>=49) -> coop V-transpose -> PV ->
// swizzled attn blob. 3 barriers, 16 MFMA/wave, 32 KB LDS.
// ---------------------------------------------------------------------------
__global__ __launch_bounds__(256) void k_attn2(
    const bf16* __restrict__ qkv,     // chunk-local [3][648][8][4096]
    const bf16* __restrict__ rpew,    // [8][49pad][64]
    char* __restrict__ attnb,         // [2592*64 rows][1024B] swizzled
    int wi0)                          // first global window of chunk
{
  __shared__ __align__(16) char sQ[8192];
  __shared__ __align__(16) char sK[8192];
  __shared__ __align__(16) char sV[8192];
  __shared__ __align__(16) char sP[8192];

  const int tid = threadIdx.x, lane = tid & 63, w = tid >> 6;
  const int r16 = lane & 15, hi = lane >> 4;
  const int g = blockIdx.x;
  const int wiL = g >> 3, h = g & 7;

  const char* qb = (const char*)(qkv + ((size_t)(0 * 648 + wiL) * 8 + h) * 4096);
  const char* kb = (const char*)(qkv + ((size_t)(1 * 648 + wiL) * 8 + h) * 4096);
  const char* vb = (const char*)(qkv + ((size_t)(2 * 648 + wiL) * 8 + h) * 4096);

  #pragma unroll
  for (int j = 0; j < 6; ++j) {
    int ch = w * 6 + j;
    int rg = ch >> 3, sub = ch & 7;
    const char* src = (rg == 0 ? qb : rg == 1 ? kb : vb) + sub * 1024 + lane * 16;
    char* dst = (rg == 0 ? sQ : rg == 1 ? sK : sV) + sub * 1024;
    gl_lds16(src, dst);
  }
  __syncthreads();

  const f32x4 fzero = {0.f, 0.f, 0.f, 0.f};

  // ---- S = q k^T (wave w owns q-rows w*16..w*16+15) ----
  f32x4 s[4];
  #pragma unroll
  for (int n = 0; n < 4; ++n) s[n] = fzero;
  #pragma unroll
  for (int k0 = 0; k0 < 2; ++k0) {
    int qrow = w * 16 + r16;
    short8 a = *reinterpret_cast<const short8*>(
        sQ + qrow * 128 + swz(qrow, k0 * 64 + hi * 16));
    #pragma unroll
    for (int n = 0; n < 4; ++n) {
      int krow = n * 16 + r16;
      short8 kf = *reinterpret_cast<const short8*>(
          sK + krow * 128 + swz(krow, k0 * 64 + hi * 16));
      s[n] = MFMA16(a, kf, s[n]);
    }
  }

  // ---- +RPE, mask, in-register softmax ----
  #pragma unroll
  for (int n = 0; n < 4; ++n) {
    int col = n * 16 + r16;
    #pragma unroll
    for (int rr = 0; rr < 4; ++rr) {
      int qrow = w * 16 + hi * 4 + rr;
      int qc = qrow < 49 ? qrow : 48;
      float sv = s[n][rr] + b2f(rpew[h * 3136 + qc * 64 + col]);
      if (col >= 49) sv = -1e30f;
      s[n][rr] = sv;
    }
  }
  #pragma unroll
  for (int rr = 0; rr < 4; ++rr) {
    float mx = fmaxf(fmaxf(s[0][rr], s[1][rr]), fmaxf(s[2][rr], s[3][rr]));
    mx = fmaxf(mx, __shfl_xor(mx, 1));
    mx = fmaxf(mx, __shfl_xor(mx, 2));
    mx = fmaxf(mx, __shfl_xor(mx, 4));
    mx = fmaxf(mx, __shfl_xor(mx, 8));
    float su = 0.f;
    #pragma unroll
    for (int n = 0; n < 4; ++n) {
      float e = __expf(s[n][rr] - mx);
      s[n][rr] = e;
      su += e;
    }
    su += __shfl_xor(su, 1);
    su += __shfl_xor(su, 2);
    su += __shfl_xor(su, 4);
    su += __shfl_xor(su, 8);
    float inv = 1.f / su;
    #pragma unroll
    for (int n = 0; n < 4; ++n) s[n][rr] *= inv;
  }

  // ---- P -> wave-private slab (A-frag layout) ----
  char* pw = sP + w * 2048;
  #pragma unroll
  for (int n = 0; n < 4; ++n)
    #pragma unroll
    for (int rr = 0; rr < 4; ++rr) {
      int rl = hi * 4 + rr, col = n * 16 + r16;
      *reinterpret_cast<bf16*>(pw + rl * 128 + swz(rl, 2 * col)) =
          __float2bfloat16(s[n][rr]);
    }

  __syncthreads();  // everyone done reading sQ/sK

  // ---- cooperative transpose: sV (linear, row=k) -> sVt (=sQ region, row=d) ----
  char* sVt = sQ;
  {
    int k = tid >> 2, c0 = (tid & 3) * 16;
    short8 v0 = *reinterpret_cast<const short8*>(sV + k * 128 + 2 * c0);
    short8 v1 = *reinterpret_cast<const short8*>(sV + k * 128 + 2 * c0 + 16);
    #pragma unroll
    for (int e = 0; e < 8; ++e) {
      int c = c0 + e;
      *reinterpret_cast<short*>(sVt + c * 128 + ((uint32_t)(2 * k) ^ ((c & 7u) << 4))) = v0[e];
      int c2 = c0 + 8 + e;
      *reinterpret_cast<short*>(sVt + c2 * 128 + ((uint32_t)(2 * k) ^ ((c2 & 7u) << 4))) = v1[e];
    }
  }
  __syncthreads();  // sVt ready

  // ---- O = P @ V ----
  f32x4 o[4];
  #pragma unroll
  for (int n = 0; n < 4; ++n) o[n] = fzero;
  #pragma unroll
  for (int k0 = 0; k0 < 2; ++k0) {
    short8 a = *reinterpret_cast<const short8*>(
        pw + r16 * 128 + swz(r16, k0 * 64 + hi * 16));
    #pragma unroll
    for (int n = 0; n < 4; ++n) {
      int d = n * 16 + r16;
      short8 vf = *reinterpret_cast<const short8*>(
          sVt + d * 128 + swz(d, k0 * 64 + hi * 16));
      o[n] = MFMA16(a, vf, o[n]);
    }
  }

  // ---- write O (all 64 rows; pad rows finite garbage, discarded later) ----
  const size_t obase = (size_t)(wi0 + wiL) * 65536 + (size_t)h * 128;
  #pragma unroll
  for (int n = 0; n < 4; ++n) {
    int d = n * 16 + r16;
    #pragma unroll
    for (int r = 0; r < 4; ++r) {
      int row = w * 16 + hi * 4 + r;
      *reinterpret_cast<bf16*>(attnb + obase + (size_t)row * 1024 +
                               ((uint32_t)(2 * d) ^ ((row & 7u) << 4))) =
          __float2bfloat16(o[n][r]);
    }
  }
}

// ---------------------------------------------------------------------------
// k_out_gemm: out = attn @ wo^T + bo, f32 un-permute scatter. m97 structure.
// grid = 1296 (mb) x 4 (nb); block 256 / 4 waves; LDS 32 KB.
// ---------------------------------------------------------------------------
__global__ __launch_bounds__(256) void k_out_gemm(
    const char* __restrict__ attnb,   // [165888][1024B] swizzled
    const char* __restrict__ wob,     // [512][1024B] swizzled
    const bf16* __restrict__ bob,     // [512]
    float* __restrict__ out)          // [8*15876][512] f32
{
  __shared__ __align__(16) char sA[16384];
  __shared__ __align__(16) char sB[16384];

  const int tid = threadIdx.x, lane = tid & 63, w = tid >> 6;
  const int r16 = lane & 15, hi = lane >> 4;
  const int mb = blockIdx.x % 1296, nb = blockIdx.x / 1296;

  const f32x4 fzero = {0.f, 0.f, 0.f, 0.f};
  f32x4 acc[4][4];
  #pragma unroll
  for (int m = 0; m < 4; ++m)
    #pragma unroll
    for (int n = 0; n < 4; ++n) acc[m][n] = fzero;

  const char* Abase = attnb + (size_t)mb * 131072;
  const char* Bbase = wob + (size_t)nb * 131072;

  for (int k0 = 0; k0 < 8; ++k0) {
    if (k0) __syncthreads();
    #pragma unroll
    for (int j = 0; j < 8; ++j) {
      int ch = w * 8 + j;
      if (ch < 16) {
        gl_lds16(Abase + (size_t)(ch * 8 + (lane >> 3)) * 1024 + k0 * 128 + (lane & 7) * 16,
                 sA + ch * 1024);
      } else {
        int c2 = ch - 16;
        gl_lds16(Bbase + (size_t)(c2 * 8 + (lane >> 3)) * 1024 + k0 * 128 + (lane & 7) * 16,
                 sB + c2 * 1024);
      }
    }
    __syncthreads();

    #pragma unroll
    for (int ks = 0; ks < 2; ++ks) {
      uint32_t cb = (uint32_t)((ks * 4 + hi) * 16) ^ ((r16 & 7u) << 4);
      short8 aF[4], bF[4];
      #pragma unroll
      for (int m = 0; m < 4; ++m)
        aF[m] = *reinterpret_cast<const short8*>(sA + ((w & 1) * 64 + m * 16 + r16) * 128 + cb);
      #pragma unroll
      for (int n = 0; n < 4; ++n)
        bF[n] = *reinterpret_cast<const short8*>(sB + ((w >> 1) * 64 + n * 16 + r16) * 128 + cb);
      #pragma unroll
      for (int m = 0; m < 4; ++m)
        #pragma unroll
        for (int n = 0; n < 4; ++n)
          acc[m][n] = MFMA16(aF[m], bF[n], acc[m][n]);
    }
  }

  // epilogue: bias + f32 un-permute scatter (rows >= 49 discarded)
  const int wi = mb * 2 + (w & 1);
  const int bb = wi / 324, qr = wi - bb * 324, qi = qr / 18, qj = qr - qi * 18;
  const int rowBase = bb * 15876 + qi * 882 + qj * 7;
  const int colb = nb * 128 + (w >> 1) * 64;

  #pragma unroll
  for (int n = 0; n < 4; ++n) {
    int col = colb + n * 16 + r16;
    float bias = b2f(bob[col]);
    #pragma unroll
    for (int m = 0; m < 4; ++m)
      #pragma unroll
      for (int r = 0; r < 4; ++r) {
        int row = m * 16 + hi * 4 + r;
        if (row < 49)
          out[(size_t)(rowBase + (row / 7) * 126 + row % 7) * 512 + col] =
              acc[m][n][r] + bias;
      }
  }
}

extern "C" void kernel_launch(void* const* d_in, const int* in_sizes, int n_in,
                              void* d_out, int out_size, void* d_ws, size_t ws_size,
                              hipStream_t stream) {
  const void* x      = d_in[0];
  const void* wqkv   = d_in[1];
  const void* bqkv   = d_in[2];
  const void* wo     = d_in[3];
  const void* bo     = d_in[4];
  const void* rpe    = d_in[5];
  const int*  relidx = (const int*)d_in[6];

  char* ws = (char*)d_ws;
  int* dflag = (int*)ws;

  // workspace layout (chunked: 4 window-groups of 648; total ~299.4 MB,
  // proven to fit since round-4's 342 MB path ran)
  const size_t OFF_XWIN = 256;
  const size_t SZ_XWIN  = 2592ull * 64 * 1024;       // 169,869,312 (xwin; later attn blob)
  const size_t OFF_WQKV = OFF_XWIN + SZ_XWIN;
  const size_t OFF_WO   = OFF_WQKV + 1536ull * 1024;
  const size_t OFF_BQKV = OFF_WO + 512ull * 1024;
  const size_t OFF_BO   = OFF_BQKV + 3072;
  const size_t OFF_RPEW = OFF_BO + 1024;
  const size_t OFF_QKV  = OFF_RPEW + 50176;          // 3*648*8*8192 = 127,401,984

  char* xwinb = ws + OFF_XWIN;     // doubles as attn blob (aliased safely per-chunk)
  char* wqkvb = ws + OFF_WQKV;
  char* wob   = ws + OFF_WO;
  bf16* bqkvb = (bf16*)(ws + OFF_BQKV);
  bf16* bob   = (bf16*)(ws + OFF_BO);
  bf16* rpew  = (bf16*)(ws + OFF_RPEW);
  bf16* qkvb  = (bf16*)(ws + OFF_QKV);

  k_probe<<<dim3(1), dim3(64), 0, stream>>>((const unsigned short*)x, dflag);
  k_conv_x2<<<dim3(41472), dim3(256), 0, stream>>>(x, xwinb, dflag);
  k_conv_w2<<<dim3(521), dim3(256), 0, stream>>>(wqkv, bqkv, wo, bo, rpe, relidx,
                                                 wqkvb, bqkvb, wob, bob, rpew, dflag);
  for (int c = 0; c < 4; ++c) {
    k_qkv_gemm<<<dim3(324 * 12), dim3(256), 0, stream>>>(xwinb, wqkvb, bqkvb, qkvb,
                                                         c * 41472);
    k_attn2<<<dim3(648 * 8), dim3(256), 0, stream>>>(qkvb, rpew, xwinb, c * 648);
  }
  k_out_gemm<<<dim3(1296 * 4), dim3(256), 0, stream>>>(xwinb, wob, bob, (float*)d_out);
}